// Round 13
// baseline (59.457 us; speedup 1.0000x reference)
//
#include <hip/hip_runtime.h>
#include <math.h>

#define NN 8192
#define DD 128
#define NSB 32        // 256-row super-blocks
#define NBLK (NSB * (NSB + 1) / 2)   // 528 triangle blocks

typedef __attribute__((ext_vector_type(4))) int i32x4;

// ws byte offsets
#define WS_SJC 0                          // 8192 * float4 = 128 KB
#define WS_HPK (NN * 16)                  // 32 KB (uint keys)
#define WS_HNK (WS_HPK + NN * 4)          // 32 KB
#define WS_AH  (WS_HNK + NN * 4)          // 1 MB (fragment-contiguous layout)
#define WS_AL  (WS_AH + NN * DD)          // 1 MB

// order-preserving float -> uint key (unsigned compare == float compare)
__device__ __forceinline__ unsigned fkey(float f) {
    unsigned u = __float_as_uint(f);
    return (u & 0x80000000u) ? ~u : (u | 0x80000000u);
}
__device__ __forceinline__ float fkey_inv(unsigned k) {
    unsigned u = (k & 0x80000000u) ? (k ^ 0x80000000u) : ~k;
    return __uint_as_float(u);
}

// fused: per-row sqnorm + absmax + i8 hi/lo quantize + metadata pack + key init
// quantized ints stored FRAGMENT-CONTIGUOUS:
//   int_index(row, k) = (row>>4)*512 + (k>>4)*256 + ((k>>2)&3)*64 + (row&15)*4 + (k&3)
__global__ __launch_bounds__(256)
void prepq_k(const float* __restrict__ emb, const int* __restrict__ lab,
             float4* __restrict__ sjc, unsigned* __restrict__ hpK,
             unsigned* __restrict__ hnK, int* __restrict__ aH, int* __restrict__ aL) {
    const int lane = threadIdx.x & 63;
    const int w    = threadIdx.x >> 6;
    const int half = lane >> 5;
    const int l32  = lane & 31;
    const int row  = blockIdx.x * 8 + w * 2 + half;

    float4 v = reinterpret_cast<const float4*>(emb)[row * 32 + l32];
    float s = 0.f, m = 0.f;
    s = fmaf(v.x, v.x, s); m = fmaxf(m, fabsf(v.x));
    s = fmaf(v.y, v.y, s); m = fmaxf(m, fabsf(v.y));
    s = fmaf(v.z, v.z, s); m = fmaxf(m, fabsf(v.z));
    s = fmaf(v.w, v.w, s); m = fmaxf(m, fabsf(v.w));
#pragma unroll
    for (int off = 1; off < 32; off <<= 1) {   // stays within the 32-lane half
        s += __shfl_xor(s, off, 64);
        m = fmaxf(m, __shfl_xor(m, off, 64));
    }
    m = fmaxf(m, 1e-30f);
    float sA  = m * (1.0f / 127.0f);
    float inv = 127.0f / m;
    int h = 0, l = 0;
#define QSTEP(X, K) { \
        float a = rintf((X) * inv); \
        a = fminf(fmaxf(a, -127.f), 127.f); \
        float r = fmaf(-a, sA, (X)); \
        float b = rintf(r * inv * 256.0f); \
        b = fminf(fmaxf(b, -127.f), 127.f); \
        h |= ((int)a & 255) << (8 * (K)); \
        l |= ((int)b & 255) << (8 * (K)); }
    QSTEP(v.x, 0) QSTEP(v.y, 1) QSTEP(v.z, 2) QSTEP(v.w, 3)
#undef QSTEP
    // fragment-contiguous scatter (k_int = l32)
    const int nidx = (row >> 4) * 512 + (l32 >> 4) * 256 + ((l32 >> 2) & 3) * 64
                   + (row & 15) * 4 + (l32 & 3);
    aH[nidx] = h;
    aL[nidx] = l;
    if (l32 == 0) {
        // ci = sA * sqrt(2)/16 so ci_i*ci_j = 2*sAi*sAj/256
        sjc[row] = make_float4(s, sA * 0.08838834764831845f,
                               __int_as_float(lab[row]), 0.f);
    }
    if (threadIdx.x < 8) {
        int r0 = blockIdx.x * 8 + threadIdx.x;
        hpK[r0] = 0x007FFFFFu;   // fkey(-inf)
        hnK[r0] = 0xFF800000u;   // fkey(+inf)
    }
}

// triangle-partitioned: block (bi<=bj) computes the 256x256 super-tile once and
// updates extrema for BOTH its rows (i-side) and cols (j-side).
__global__ __launch_bounds__(256, 2)
void hardest_k(const int* __restrict__ aH, const int* __restrict__ aL,
               const float4* __restrict__ sjc,
               unsigned* __restrict__ hpK, unsigned* __restrict__ hnK) {
    const int tid  = threadIdx.x;
    const int w    = tid >> 6;
    const int lane = tid & 63;
    const int lrow = lane & 15;
    const int lk   = lane >> 4;

    // map blockIdx -> (bi, bj) in the upper triangle (bi <= bj)
    int rem = (int)blockIdx.x, bi = 0;
    while (rem >= NSB - bi) { rem -= NSB - bi; ++bi; }
    const int bj = bi + rem;
    const int i0     = bi * 256;
    const int j0base = bj * 256;

    // persistent A fragments: 4 strips of 16 rows, K=128 in 2 chunks, hi+lo
    i32x4 ah[4][2], al[4][2];
#pragma unroll
    for (int s = 0; s < 4; ++s) {
        const int gA = bi * 16 + w * 4 + s;
#pragma unroll
        for (int q = 0; q < 2; ++q) {
            ah[s][q] = *reinterpret_cast<const i32x4*>(&aH[gA * 512 + q * 256 + lane * 4]);
            al[s][q] = *reinterpret_cast<const i32x4*>(&aL[gA * 512 + q * 256 + lane * 4]);
        }
    }
    int   li[4][4];
    float cih[4][4], sqA[4][4], hpg[4][4], hng[4][4];
#pragma unroll
    for (int s = 0; s < 4; ++s)
#pragma unroll
        for (int t = 0; t < 4; ++t) {
            float4 mdv = sjc[i0 + w * 64 + s * 16 + lk * 4 + t];
            sqA[s][t] = mdv.x;
            cih[s][t] = mdv.y;
            li[s][t]  = __float_as_int(mdv.z);
            hpg[s][t] = -INFINITY;
            hng[s][t] =  INFINITY;
        }

#pragma unroll 1
    for (int c = 0; c < 16; ++c) {
        const int gB = bj * 16 + c;
        const int bb = gB * 512 + lane * 4;
        i32x4 bh0 = *reinterpret_cast<const i32x4*>(&aH[bb]);
        i32x4 bh1 = *reinterpret_cast<const i32x4*>(&aH[bb + 256]);
        i32x4 bl0 = *reinterpret_cast<const i32x4*>(&aL[bb]);
        i32x4 bl1 = *reinterpret_cast<const i32x4*>(&aL[bb + 256]);
        float4 sv = sjc[j0base + c * 16 + lrow];
        i32x4 accA[4], accB[4];
        i32x4 zero = {0, 0, 0, 0};
#pragma unroll
        for (int s = 0; s < 4; ++s) { accA[s] = zero; accB[s] = zero; }
#pragma unroll
        for (int s = 0; s < 4; ++s) {
            accA[s] = __builtin_amdgcn_mfma_i32_16x16x64_i8(ah[s][0], bh0, accA[s], 0, 0, 0);
            accA[s] = __builtin_amdgcn_mfma_i32_16x16x64_i8(ah[s][1], bh1, accA[s], 0, 0, 0);
            accB[s] = __builtin_amdgcn_mfma_i32_16x16x64_i8(ah[s][0], bl0, accB[s], 0, 0, 0);
            accB[s] = __builtin_amdgcn_mfma_i32_16x16x64_i8(ah[s][1], bl1, accB[s], 0, 0, 0);
            accB[s] = __builtin_amdgcn_mfma_i32_16x16x64_i8(al[s][0], bh0, accB[s], 0, 0, 0);
            accB[s] = __builtin_amdgcn_mfma_i32_16x16x64_i8(al[s][1], bh1, accB[s], 0, 0, 0);
        }
        const float sqj = sv.x;
        const float cjv = sv.y;
        const int   lj  = __float_as_int(sv.z);
        float cp = -INFINITY, cn = INFINITY;
#pragma unroll
        for (int s = 0; s < 4; ++s)
#pragma unroll
            for (int t = 0; t < 4; ++t) {
                int   e  = (accA[s][t] << 8) + accB[s][t];    // exact, < 2^30
                float ef = (float)e;
                float mm = cih[s][t] * cjv;                   // 2*sAi*sAj/256
                float gg = fmaf(mm, -ef, sqj);                // row-i value: sqj - 2dot
                float vv = fmaf(mm, -ef, sqA[s][t]);          // col-j value: sqi - 2dot
                bool same = (li[s][t] == lj);
                hpg[s][t] = fmaxf(hpg[s][t], same ? gg : -INFINITY);
                hng[s][t] = fminf(hng[s][t], same ? INFINITY : gg);
                cp = fmaxf(cp, same ? vv : -INFINITY);
                cn = fminf(cn, same ? INFINITY : vv);
            }
        // col-side flush: reduce over the 4 lk groups (lanes sharing lrow)
        cp = fmaxf(cp, __shfl_xor(cp, 16, 64));
        cp = fmaxf(cp, __shfl_xor(cp, 32, 64));
        cn = fminf(cn, __shfl_xor(cn, 16, 64));
        cn = fminf(cn, __shfl_xor(cn, 32, 64));
        if (lk == 0) {
            int j = j0base + c * 16 + lrow;
            atomicMax(&hpK[j], fkey(cp));   // order-independent => deterministic
            atomicMin(&hnK[j], fkey(cn));
        }
    }

    // row-side: reduce over the 16 column-lanes sharing each output row
#pragma unroll
    for (int off = 1; off < 16; off <<= 1)
#pragma unroll
        for (int s = 0; s < 4; ++s)
#pragma unroll
            for (int t = 0; t < 4; ++t) {
                hpg[s][t] = fmaxf(hpg[s][t], __shfl_xor(hpg[s][t], off, 64));
                hng[s][t] = fminf(hng[s][t], __shfl_xor(hng[s][t], off, 64));
            }
    if (lrow == 0) {
#pragma unroll
        for (int s = 0; s < 4; ++s)
#pragma unroll
            for (int t = 0; t < 4; ++t) {
                int i = i0 + w * 64 + s * 16 + lk * 4 + t;
                atomicMax(&hpK[i], fkey(hpg[s][t]));
                atomicMin(&hnK[i], fkey(hng[s][t]));
            }
    }
}

__global__ __launch_bounds__(1024)
void final_k(const unsigned* __restrict__ hpK, const unsigned* __restrict__ hnK,
             const float4* __restrict__ sjc, float* __restrict__ out) {
    float total = 0.f, cnt = 0.f;
    for (int i = threadIdx.x; i < NN; i += 1024) {
        float hp = fkey_inv(hpK[i]);
        float hn = fkey_inv(hnK[i]);
        float s  = sjc[i].x;
        float hp2 = s + hp, hn2 = s + hn;                 // d^2 = sq_i + g
        float hpd = (hp2 == -INFINITY) ? -INFINITY : sqrtf(fmaxf(hp2, 0.f));
        float hnd = (hn2 ==  INFINITY) ?  INFINITY : sqrtf(fmaxf(hn2, 0.f));
        float tl = hpd - hnd + 1.0f;                      // -inf propagates, no NaN
        if (tl > 0.f) { total += tl; cnt += 1.f; }
    }
#pragma unroll
    for (int off = 1; off < 64; off <<= 1) {
        total += __shfl_xor(total, off, 64);
        cnt   += __shfl_xor(cnt,   off, 64);
    }
    __shared__ float sT[16], sC[16];
    int wave = threadIdx.x >> 6;
    if ((threadIdx.x & 63) == 0) { sT[wave] = total; sC[wave] = cnt; }
    __syncthreads();
    if (threadIdx.x == 0) {
        float T = 0.f, Cn = 0.f;
#pragma unroll
        for (int k = 0; k < 16; ++k) { T += sT[k]; Cn += sC[k]; }
        out[0] = (Cn > 0.f) ? T / Cn : 0.f;
    }
}

extern "C" void kernel_launch(void* const* d_in, const int* in_sizes, int n_in,
                              void* d_out, int out_size, void* d_ws, size_t ws_size,
                              hipStream_t stream) {
    const float* emb = (const float*)d_in[0];
    const int*   lab = (const int*)d_in[1];
    char* ws = (char*)d_ws;
    float4*   sjc = (float4*)(ws + WS_SJC);
    unsigned* hpK = (unsigned*)(ws + WS_HPK);
    unsigned* hnK = (unsigned*)(ws + WS_HNK);
    int*      aH  = (int*)(ws + WS_AH);
    int*      aL  = (int*)(ws + WS_AL);

    prepq_k<<<dim3(NN / 8), dim3(256), 0, stream>>>(emb, lab, sjc, hpK, hnK, aH, aL);
    hardest_k<<<dim3(NBLK), dim3(256), 0, stream>>>(aH, aL, sjc, hpK, hnK);
    final_k<<<dim3(1), dim3(1024), 0, stream>>>(hpK, hnK, sjc, (float*)d_out);
}

// Round 14
// 41.179 us; speedup vs baseline: 1.4439x; 1.4439x over previous
//
#include <hip/hip_runtime.h>
#include <hip/hip_bf16.h>
#include <math.h>

#define NN 8192
#define DD 128
#define BM 256        // rows per block (4 waves x 64)
#define BN 64         // cols per j-tile
#define NPART 16      // grid = 32*16 = 512 blocks (2 blocks/CU, single batch)
#define JRANGE (NN / NPART)    // 512
#define NTILES (JRANGE / BN)   // 8

typedef __attribute__((ext_vector_type(8))) short bf16x8;
typedef __attribute__((ext_vector_type(4))) float f32x4;

// ws byte offsets
#define WS_SJC 0                          // 8192 * float2 = 64 KB
#define WS_HPK 65536                      // 32 KB (uint keys)
#define WS_HNK (WS_HPK + NN * 4)          // 32 KB
#define WS_AB  (WS_HNK + NN * 4)          // 2 MB (bf16, fragment-contiguous)

// order-preserving float -> uint key (unsigned compare == float compare)
__device__ __forceinline__ unsigned fkey(float f) {
    unsigned u = __float_as_uint(f);
    return (u & 0x80000000u) ? ~u : (u | 0x80000000u);
}
__device__ __forceinline__ float fkey_inv(unsigned k) {
    unsigned u = (k & 0x80000000u) ? (k ^ 0x80000000u) : ~k;
    return __uint_as_float(u);
}
__device__ __forceinline__ ushort f2bf(float x) {
    __hip_bfloat16 h = __float2bfloat16(x);
    return *reinterpret_cast<ushort*>(&h);
}

// fused: fp32 sqnorm + bf16 convert (fragment-contiguous) + metadata + key init
// bf16 ushort index(row,k) = (row>>4)*2048 + (k>>5)*512 + ((k>>3)&3)*128
//                          + (row&15)*8 + (k&7)
// => wave fragment (group g, kchunk q) load = &aB[g*2048 + q*512 + lane*8], 16B/lane
__global__ __launch_bounds__(256)
void prepq_k(const float* __restrict__ emb, const int* __restrict__ lab,
             float2* __restrict__ sjc, unsigned* __restrict__ hpK,
             unsigned* __restrict__ hnK, ushort* __restrict__ aB) {
    const int lane = threadIdx.x & 63;
    const int w    = threadIdx.x >> 6;
    const int half = lane >> 5;
    const int l32  = lane & 31;
    const int row  = blockIdx.x * 8 + w * 2 + half;

    float4 v = reinterpret_cast<const float4*>(emb)[row * 32 + l32];
    float s = 0.f;
    s = fmaf(v.x, v.x, s); s = fmaf(v.y, v.y, s);
    s = fmaf(v.z, v.z, s); s = fmaf(v.w, v.w, s);
#pragma unroll
    for (int off = 1; off < 32; off <<= 1) s += __shfl_xor(s, off, 64);

    ushort4 b;
    b.x = f2bf(v.x); b.y = f2bf(v.y); b.z = f2bf(v.z); b.w = f2bf(v.w);
    // k = l32*4 .. l32*4+3  ->  q = l32>>3, lk = (l32>>1)&3, e0 = (l32&1)*4
    const int idx = (row >> 4) * 2048 + (l32 >> 3) * 512 + ((l32 >> 1) & 3) * 128
                  + (row & 15) * 8 + (l32 & 1) * 4;
    *reinterpret_cast<ushort4*>(aB + idx) = b;

    if (l32 == 0) sjc[row] = make_float2(s, __int_as_float(lab[row]));
    if (threadIdx.x < 8) {
        int r0 = blockIdx.x * 8 + threadIdx.x;
        hpK[r0] = 0x007FFFFFu;   // fkey(-inf)
        hnK[r0] = 0xFF800000u;   // fkey(+inf)
    }
}

__global__ __launch_bounds__(256, 2)
void hardest_k(const ushort* __restrict__ aB, const float2* __restrict__ sjc,
               unsigned* __restrict__ hpK, unsigned* __restrict__ hnK) {
    const int tid  = threadIdx.x;
    const int w    = tid >> 6;
    const int lane = tid & 63;
    const int lrow = lane & 15;
    const int lk   = lane >> 4;
    const int ib   = (int)blockIdx.x >> 4;    // 0..31
    const int part = (int)blockIdx.x & 15;    // 0..15
    const int i0   = ib * BM;
    const int jbeg = part * JRANGE;

    // persistent A fragments: 4 strips of 16 rows x 4 k-chunks (64 VGPR)
    bf16x8 a[4][4];
#pragma unroll
    for (int s = 0; s < 4; ++s) {
        const int gA = ib * 16 + w * 4 + s;
#pragma unroll
        for (int q = 0; q < 4; ++q)
            a[s][q] = *reinterpret_cast<const bf16x8*>(&aB[gA * 2048 + q * 512 + lane * 8]);
    }
    int   li[4][4];
    float hpg[4][4], hng[4][4];
#pragma unroll
    for (int s = 0; s < 4; ++s)
#pragma unroll
        for (int t = 0; t < 4; ++t) {
            float2 md = sjc[i0 + w * 64 + s * 16 + lk * 4 + t];
            li[s][t]  = __float_as_int(md.y);
            hpg[s][t] = -INFINITY;
            hng[s][t] =  INFINITY;
        }

#pragma unroll 1
    for (int jt = 0; jt < NTILES; ++jt) {
        const int j0 = jbeg + jt * BN;
#pragma unroll
        for (int c = 0; c < 4; ++c) {
            const int gB = (j0 >> 4) + c;
            const ushort* bp = &aB[gB * 2048 + lane * 8];
            bf16x8 b0 = *reinterpret_cast<const bf16x8*>(bp);
            bf16x8 b1 = *reinterpret_cast<const bf16x8*>(bp + 512);
            bf16x8 b2 = *reinterpret_cast<const bf16x8*>(bp + 1024);
            bf16x8 b3 = *reinterpret_cast<const bf16x8*>(bp + 1536);
            float2 sv = sjc[j0 + c * 16 + lrow];
            f32x4 acc[4];
            f32x4 zero = {0.f, 0.f, 0.f, 0.f};
#pragma unroll
            for (int s = 0; s < 4; ++s) acc[s] = zero;
#pragma unroll
            for (int s = 0; s < 4; ++s) {
                acc[s] = __builtin_amdgcn_mfma_f32_16x16x32_bf16(a[s][0], b0, acc[s], 0, 0, 0);
                acc[s] = __builtin_amdgcn_mfma_f32_16x16x32_bf16(a[s][1], b1, acc[s], 0, 0, 0);
                acc[s] = __builtin_amdgcn_mfma_f32_16x16x32_bf16(a[s][2], b2, acc[s], 0, 0, 0);
                acc[s] = __builtin_amdgcn_mfma_f32_16x16x32_bf16(a[s][3], b3, acc[s], 0, 0, 0);
            }
            const float sqj = sv.x;
            const int   lj  = __float_as_int(sv.y);
#pragma unroll
            for (int s = 0; s < 4; ++s)
#pragma unroll
                for (int t = 0; t < 4; ++t) {
                    float gg = fmaf(-2.f, acc[s][t], sqj);        // g = sqj - 2*dot
                    bool same = (li[s][t] == lj);
                    hpg[s][t] = fmaxf(hpg[s][t], same ? gg : -INFINITY);
                    hng[s][t] = fminf(hng[s][t], same ? INFINITY : gg);
                }
        }
    }

    // reduce over the 16 column-lanes sharing each output row
#pragma unroll
    for (int off = 1; off < 16; off <<= 1)
#pragma unroll
        for (int s = 0; s < 4; ++s)
#pragma unroll
            for (int t = 0; t < 4; ++t) {
                hpg[s][t] = fmaxf(hpg[s][t], __shfl_xor(hpg[s][t], off, 64));
                hng[s][t] = fminf(hng[s][t], __shfl_xor(hng[s][t], off, 64));
            }
    if (lrow == 0) {
#pragma unroll
        for (int s = 0; s < 4; ++s)
#pragma unroll
            for (int t = 0; t < 4; ++t) {
                int i = i0 + w * 64 + s * 16 + lk * 4 + t;
                atomicMax(&hpK[i], fkey(hpg[s][t]));   // order-independent => deterministic
                atomicMin(&hnK[i], fkey(hng[s][t]));
            }
    }
}

__global__ __launch_bounds__(1024)
void final_k(const unsigned* __restrict__ hpK, const unsigned* __restrict__ hnK,
             const float2* __restrict__ sjc, float* __restrict__ out) {
    float total = 0.f, cnt = 0.f;
    for (int i = threadIdx.x; i < NN; i += 1024) {
        float hp = fkey_inv(hpK[i]);
        float hn = fkey_inv(hnK[i]);
        float s  = sjc[i].x;
        float hp2 = s + hp, hn2 = s + hn;                 // d^2 = sq_i + g
        float hpd = (hp2 == -INFINITY) ? -INFINITY : sqrtf(fmaxf(hp2, 0.f));
        float hnd = (hn2 ==  INFINITY) ?  INFINITY : sqrtf(fmaxf(hn2, 0.f));
        float tl = hpd - hnd + 1.0f;                      // -inf propagates, no NaN
        if (tl > 0.f) { total += tl; cnt += 1.f; }
    }
#pragma unroll
    for (int off = 1; off < 64; off <<= 1) {
        total += __shfl_xor(total, off, 64);
        cnt   += __shfl_xor(cnt,   off, 64);
    }
    __shared__ float sT[16], sC[16];
    int wave = threadIdx.x >> 6;
    if ((threadIdx.x & 63) == 0) { sT[wave] = total; sC[wave] = cnt; }
    __syncthreads();
    if (threadIdx.x == 0) {
        float T = 0.f, Cn = 0.f;
#pragma unroll
        for (int k = 0; k < 16; ++k) { T += sT[k]; Cn += sC[k]; }
        out[0] = (Cn > 0.f) ? T / Cn : 0.f;
    }
}

extern "C" void kernel_launch(void* const* d_in, const int* in_sizes, int n_in,
                              void* d_out, int out_size, void* d_ws, size_t ws_size,
                              hipStream_t stream) {
    const float* emb = (const float*)d_in[0];
    const int*   lab = (const int*)d_in[1];
    char* ws = (char*)d_ws;
    float2*   sjc = (float2*)(ws + WS_SJC);
    unsigned* hpK = (unsigned*)(ws + WS_HPK);
    unsigned* hnK = (unsigned*)(ws + WS_HNK);
    ushort*   aB  = (ushort*)(ws + WS_AB);

    prepq_k<<<dim3(NN / 8), dim3(256), 0, stream>>>(emb, lab, sjc, hpK, hnK, aB);
    hardest_k<<<dim3((NN / BM) * NPART), dim3(256), 0, stream>>>(aB, sjc, hpK, hnK);
    final_k<<<dim3(1), dim3(1024), 0, stream>>>(hpK, hnK, sjc, (float*)d_out);
}